// Round 1
// baseline (101.471 us; speedup 1.0000x reference)
//
#include <hip/hip_runtime.h>
#include <hip/hip_bf16.h>
#include <math.h>

// Problem constants (fixed by setup_inputs)
#define B_DIM 16
#define T_DIM 100
#define HW_PIX (27 * 48)      // 1296 pixels per frame
#define NBINS 512
#define WIN 101               // lookup window
#define HALF 50
#define ODIM 128

// ---------------------------------------------------------------------------
// Kernel 1: per-frame 512-bin histogram, L2-normalized, written as f32.
// One block per frame (B*T = 1600 blocks), 256 threads.
// ---------------------------------------------------------------------------
__global__ __launch_bounds__(256) void hist_kernel(
    const int* __restrict__ frames, float* __restrict__ hist) {
  __shared__ int h[NBINS];
  __shared__ float red[16];

  const int f = blockIdx.x;          // frame index 0..1599
  const int tid = threadIdx.x;       // 0..255

  for (int i = tid; i < NBINS; i += 256) h[i] = 0;
  __syncthreads();

  const int* fp = frames + (size_t)f * (HW_PIX * 3);
  for (int p = tid; p < HW_PIX; p += 256) {
    int r = fp[p * 3 + 0];
    int g = fp[p * 3 + 1];
    int b = fp[p * 3 + 2];
    int bin = ((r >> 5) << 6) + ((g >> 5) << 3) + (b >> 5);
    atomicAdd(&h[bin], 1);
  }
  __syncthreads();

  // sum of squares across 512 bins (2 bins per thread)
  float ss = 0.f;
  for (int i = tid; i < NBINS; i += 256) {
    float v = (float)h[i];
    ss += v * v;
  }
  const int lane = tid & 63, wave = tid >> 6;
#pragma unroll
  for (int off = 32; off > 0; off >>= 1) ss += __shfl_down(ss, off);
  if (lane == 0) red[wave] = ss;
  __syncthreads();
  if (tid == 0) {
    float tot = red[0] + red[1] + red[2] + red[3];
    red[8] = 1.0f / sqrtf(tot);
  }
  __syncthreads();
  const float rn = red[8];

  float* hp = hist + (size_t)f * NBINS;
  for (int i = tid; i < NBINS; i += 256) hp[i] = (float)h[i] * rn;
}

// ---------------------------------------------------------------------------
// Kernel 2: banded self-similarity + FC(101->128) + ReLU.
// One block per (b,t) = 1600 blocks, 256 threads (4 waves).
//   band[j] = <x[b,t,:], x[b,t+j-50,:]>  (0 if out of range), j in [0,101)
//   out[b,t,d] = relu(sum_j band[j]*fc_w[j,d] + fc_b[d])
// ---------------------------------------------------------------------------
__global__ __launch_bounds__(256) void band_fc_kernel(
    const float* __restrict__ hist, const float* __restrict__ fc_w,
    const float* __restrict__ fc_b, float* __restrict__ out) {
  __shared__ float xq[NBINS];
  __shared__ float band[WIN];

  const int bt = blockIdx.x;     // 0..1599
  const int b = bt / T_DIM;
  const int t = bt - b * T_DIM;
  const int tid = threadIdx.x;
  const int lane = tid & 63, wave = tid >> 6;

  // stage x[b,t,:] in LDS
  const float* xrow = hist + (size_t)bt * NBINS;
  for (int i = tid; i < NBINS; i += 256) xq[i] = xrow[i];
  __syncthreads();

  // 101 dot products, distributed over the 4 waves
  for (int j = wave; j < WIN; j += 4) {
    const int s = t + j - HALF;
    float dot = 0.f;
    if (s >= 0 && s < T_DIM) {
      const float* xs = hist + ((size_t)(b * T_DIM + s)) * NBINS;
#pragma unroll
      for (int k = 0; k < 8; ++k) {
        dot += xq[lane + 64 * k] * xs[lane + 64 * k];
      }
#pragma unroll
      for (int off = 32; off > 0; off >>= 1) dot += __shfl_down(dot, off);
    }
    if (lane == 0) band[j] = dot;  // dot==0 when s out of range
  }
  __syncthreads();

  // FC: 128 output dims, first 128 threads each own one dim
  if (tid < ODIM) {
    float acc = fc_b[tid];
#pragma unroll 4
    for (int j = 0; j < WIN; ++j) acc += band[j] * fc_w[j * ODIM + tid];
    out[(size_t)bt * ODIM + tid] = fmaxf(acc, 0.f);
  }
}

extern "C" void kernel_launch(void* const* d_in, const int* in_sizes, int n_in,
                              void* d_out, int out_size, void* d_ws, size_t ws_size,
                              hipStream_t stream) {
  const int* frames = (const int*)d_in[0];     // (16,100,27,48,3) int32
  const float* fc_w = (const float*)d_in[1];   // (101,128) f32
  const float* fc_b = (const float*)d_in[2];   // (128,) f32
  float* out = (float*)d_out;                  // (16,100,128) f32
  float* hist = (float*)d_ws;                  // 1600*512 f32 = 3.28 MB scratch

  hist_kernel<<<B_DIM * T_DIM, 256, 0, stream>>>(frames, hist);
  band_fc_kernel<<<B_DIM * T_DIM, 256, 0, stream>>>(hist, fc_w, fc_b, out);
}

// Round 2
// 88.321 us; speedup vs baseline: 1.1489x; 1.1489x over previous
//
#include <hip/hip_runtime.h>
#include <hip/hip_bf16.h>
#include <math.h>

#define B_DIM 16
#define T_DIM 100
#define TPAD 112            // 7 MFMA row-tiles of 16
#define HW_PIX (27 * 48)    // 1296 pixels/frame
#define NBINS 512
#define WIN 101
#define HALF 50
#define ODIM 128
#define NTILE 7             // TPAD/16
#define BSTRIDE 104         // band row stride in LDS (bank-offset 8/row)

typedef __attribute__((ext_vector_type(8))) short s16x8;
typedef __attribute__((ext_vector_type(4))) float f32x4;

// ---------------------------------------------------------------------------
// Kernel A: per-frame 512-bin histogram, L2-normalized, stored bf16 into
// X16[b][t][512] with rows 100..111 zeroed (MFMA padding).
// blocks 0..1599: one frame each. blocks 1600..1791: zero one pad row each.
// ---------------------------------------------------------------------------
__global__ __launch_bounds__(256) void hist_kernel(
    const int* __restrict__ frames, __hip_bfloat16* __restrict__ X16) {
  const int bid = blockIdx.x;
  const int tid = threadIdx.x;

  if (bid >= B_DIM * T_DIM) {
    // zero a pad row: rows (b*112 + 100..111)
    const int pid = bid - B_DIM * T_DIM;      // 0..191
    const int b = pid / (TPAD - T_DIM);
    const int r = pid - b * (TPAD - T_DIM);
    unsigned int* row = (unsigned int*)(X16 + ((size_t)(b * TPAD + T_DIM + r)) * NBINS);
    row[tid] = 0u;                             // 256 uints = 512 bf16
    return;
  }

  __shared__ int h[NBINS];
  __shared__ float red[16];

  for (int i = tid; i < NBINS; i += 256) h[i] = 0;
  __syncthreads();

  // 1296 pixels = 324 groups of 4 pixels (12 dwords = 3 int4 loads)
  const int* fp = frames + (size_t)bid * (HW_PIX * 3);
  for (int i = tid; i < HW_PIX / 4; i += 256) {
    const int4* q = (const int4*)(fp + 12 * i);
    int4 a = q[0], c = q[1], e = q[2];
    int b0 = ((a.x >> 5) << 6) + ((a.y >> 5) << 3) + (a.z >> 5);
    int b1 = ((a.w >> 5) << 6) + ((c.x >> 5) << 3) + (c.y >> 5);
    int b2 = ((c.z >> 5) << 6) + ((c.w >> 5) << 3) + (e.x >> 5);
    int b3 = ((e.y >> 5) << 6) + ((e.z >> 5) << 3) + (e.w >> 5);
    atomicAdd(&h[b0], 1);
    atomicAdd(&h[b1], 1);
    atomicAdd(&h[b2], 1);
    atomicAdd(&h[b3], 1);
  }
  __syncthreads();

  float ss = 0.f;
  for (int i = tid; i < NBINS; i += 256) {
    float v = (float)h[i];
    ss += v * v;
  }
  const int lane = tid & 63, wave = tid >> 6;
#pragma unroll
  for (int off = 32; off > 0; off >>= 1) ss += __shfl_down(ss, off);
  if (lane == 0) red[wave] = ss;
  __syncthreads();
  if (tid == 0) red[8] = 1.0f / sqrtf(red[0] + red[1] + red[2] + red[3]);
  __syncthreads();
  const float rn = red[8];

  const int b = bid / T_DIM;
  const int t = bid - b * T_DIM;
  __hip_bfloat16* row = X16 + ((size_t)(b * TPAD + t)) * NBINS;
  for (int i = tid; i < NBINS; i += 256) row[i] = __float2bfloat16((float)h[i] * rn);
}

// ---------------------------------------------------------------------------
// Kernel B: sim[b] = X[b] · X[b]^T via MFMA bf16 16x16x32.
// One wave per 16x16 output tile; grid = 16 batches * 49 tiles.
//   A frag: A[m=lane&15][k=quad*8+j]; B frag: B[n=lane&15][k=quad*8+j]
//   D frag: col=lane&15, row=quad*4+reg
// ---------------------------------------------------------------------------
__global__ __launch_bounds__(64) void sim_kernel(
    const __hip_bfloat16* __restrict__ X16, float* __restrict__ sim) {
  const int bid = blockIdx.x;
  const int b = bid / (NTILE * NTILE);
  const int tile = bid - b * (NTILE * NTILE);
  const int tm = tile / NTILE, tn = tile - tm * NTILE;
  const int lane = threadIdx.x;
  const int m16 = lane & 15, quad = lane >> 4;

  const short* A = (const short*)(X16 + ((size_t)(b * TPAD + tm * 16 + m16)) * NBINS) + quad * 8;
  const short* Bp = (const short*)(X16 + ((size_t)(b * TPAD + tn * 16 + m16)) * NBINS) + quad * 8;

  f32x4 acc = {0.f, 0.f, 0.f, 0.f};
#pragma unroll 4
  for (int k = 0; k < NBINS; k += 32) {
    s16x8 af = *(const s16x8*)(A + k);
    s16x8 bf = *(const s16x8*)(Bp + k);
    acc = __builtin_amdgcn_mfma_f32_16x16x32_bf16(af, bf, acc, 0, 0, 0);
  }

  const int n = tn * 16 + m16;
  if (n < T_DIM) {
    float* srow = sim + (size_t)b * T_DIM * T_DIM + n;
#pragma unroll
    for (int r = 0; r < 4; ++r) {
      int m = tm * 16 + quad * 4 + r;
      if (m < T_DIM) srow[(size_t)m * T_DIM] = acc[r];
    }
  }
}

// ---------------------------------------------------------------------------
// Kernel C: band extraction + FC(101->128) + ReLU.
// Grid = 16 batches * 7 chunks of 16 t's; 256 threads.
// LDS: fc_w (101x128 f32) + band (16 x BSTRIDE f32).
// Thread owns d-quad (g4 = tid&31 -> d=4*g4..) and tl in {tid>>5, (tid>>5)+8}.
// ---------------------------------------------------------------------------
__global__ __launch_bounds__(256) void band_fc_kernel(
    const float* __restrict__ sim, const float* __restrict__ fc_w,
    const float* __restrict__ fc_b, float* __restrict__ out) {
  __shared__ __align__(16) float wlds[WIN * ODIM];   // 51712 B
  __shared__ float blds[16 * BSTRIDE];               // 6656 B

  const int cid = blockIdx.x;
  const int b = cid / NTILE;
  const int t0 = (cid - b * NTILE) * 16;
  const int tid = threadIdx.x;

  // stage fc_w as float4
  {
    const f32x4* src = (const f32x4*)fc_w;
    f32x4* dst = (f32x4*)wlds;
    for (int i = tid; i < (WIN * ODIM) / 4; i += 256) dst[i] = src[i];
  }
  // stage band rows (zero outside valid range)
  for (int idx = tid; idx < 16 * WIN; idx += 256) {
    int tl = idx / WIN;
    int j = idx - tl * WIN;
    int t = t0 + tl;
    int s = t - HALF + j;
    float v = 0.f;
    if (t < T_DIM && s >= 0 && s < T_DIM)
      v = sim[((size_t)b * T_DIM + t) * T_DIM + s];
    blds[tl * BSTRIDE + j] = v;
  }
  __syncthreads();

  const int g4 = tid & 31;        // d = 4*g4 .. 4*g4+3
  const int tl0 = tid >> 5;       // 0..7
  const int tl1 = tl0 + 8;

  f32x4 acc0 = ((const f32x4*)fc_b)[g4];
  f32x4 acc1 = acc0;
#pragma unroll 4
  for (int j = 0; j < WIN; ++j) {
    f32x4 wv = *(const f32x4*)&wlds[j * ODIM + g4 * 4];
    float b0 = blds[tl0 * BSTRIDE + j];
    float b1 = blds[tl1 * BSTRIDE + j];
    acc0 += wv * b0;
    acc1 += wv * b1;
  }

#pragma unroll
  for (int c = 0; c < 4; ++c) {
    acc0[c] = fmaxf(acc0[c], 0.f);
    acc1[c] = fmaxf(acc1[c], 0.f);
  }

  const int t0a = t0 + tl0, t0b = t0 + tl1;
  if (t0a < T_DIM)
    *(f32x4*)&out[(((size_t)b * T_DIM + t0a)) * ODIM + g4 * 4] = acc0;
  if (t0b < T_DIM)
    *(f32x4*)&out[(((size_t)b * T_DIM + t0b)) * ODIM + g4 * 4] = acc1;
}

extern "C" void kernel_launch(void* const* d_in, const int* in_sizes, int n_in,
                              void* d_out, int out_size, void* d_ws, size_t ws_size,
                              hipStream_t stream) {
  const int* frames = (const int*)d_in[0];     // (16,100,27,48,3) int32
  const float* fc_w = (const float*)d_in[1];   // (101,128) f32
  const float* fc_b = (const float*)d_in[2];   // (128,) f32
  float* out = (float*)d_out;                  // (16,100,128) f32

  __hip_bfloat16* X16 = (__hip_bfloat16*)d_ws;                    // 16*112*512 bf16 = 1.835 MB
  float* sim = (float*)((char*)d_ws + (size_t)B_DIM * TPAD * NBINS * 2);  // 16*100*100 f32

  hist_kernel<<<B_DIM * T_DIM + B_DIM * (TPAD - T_DIM), 256, 0, stream>>>(frames, X16);
  sim_kernel<<<B_DIM * NTILE * NTILE, 64, 0, stream>>>(X16, sim);
  band_fc_kernel<<<B_DIM * NTILE, 256, 0, stream>>>(sim, fc_w, fc_b, out);
}